// Round 11
// baseline (3762.165 us; speedup 1.0000x reference)
//
#include <hip/hip_runtime.h>

#define B_   1024
#define TE   168
#define TD   24
#define F_   64
#define H_   128
#define H2_  256
#define G_   512

// ---- workspace float offsets ----
#define OFF_WMT    0          // half [128][320]  (We|Wi concat along K)
#define OFF_VdT    40960      // half [64][128]
#define OFF_eWihT  49152      // half [512][64]
#define OFF_eWhhT  81920      // half [512][128]
#define OFF_mWihT  147456     // half [512][128]
#define OFF_mWhhT  212992     // half [512][128]
#define OFF_WxT    278528     // half [128][128]
#define OFF_WhT    294912     // half pairs [128p][256]   (decoder, R10 layout)
#define OFF_dWihT  327680     // half pairs [64p][1024]
#define OFF_dWhhT  393216     // half pairs [64p][1024]
#define OFF_ENCB   458752     // float [512]
#define OFF_MIDB   459264
#define OFF_DECB   459776
#define OFF_MID    460800                      // half [1024][168][128]
#define OFF_WX     (OFF_MID + B_*TE*H_)        // half [1024][168][128]
#define OFF_STH    (OFF_WX  + B_*TE*H_)        // float [1024][128]
#define OFF_STC    (OFF_STH + B_*H_)
#define WS_FLOATS  (OFF_STC + B_*H_)

typedef _Float16 h2 __attribute__((ext_vector_type(2)));
typedef _Float16 h4 __attribute__((ext_vector_type(4)));
typedef _Float16 h8 __attribute__((ext_vector_type(8)));
typedef float    f4v __attribute__((ext_vector_type(4)));

__device__ __forceinline__ float fexp2(float x) { return __builtin_amdgcn_exp2f(x); }
__device__ __forceinline__ float frcp(float x)  { return __builtin_amdgcn_rcpf(x); }
#define LOG2E 1.4426950408889634f

__device__ __forceinline__ float sigm(float x) {
    return frcp(1.f + fexp2(-LOG2E * x));
}
__device__ __forceinline__ float tanh_fast(float x) {
    float e = fexp2(2.f * LOG2E * x);
    return 1.f - 2.f * frcp(e + 1.f);
}
__device__ __forceinline__ float fdot2(h2 a, h2 b, float c) {
#if __has_builtin(__builtin_amdgcn_fdot2)
    return __builtin_amdgcn_fdot2(a, b, c, false);
#else
    return c + (float)a[0] * (float)b[0] + (float)a[1] * (float)b[1];
#endif
}
__device__ __forceinline__ void fma4(float4& g, const float4 wv, const float s) {
    g.x = __builtin_fmaf(wv.x, s, g.x);
    g.y = __builtin_fmaf(wv.y, s, g.y);
    g.z = __builtin_fmaf(wv.z, s, g.z);
    g.w = __builtin_fmaf(wv.w, s, g.w);
}
__device__ __forceinline__ f4v mfma16(h8 a, h8 b, f4v c) {
    return __builtin_amdgcn_mfma_f32_16x16x32_f16(a, b, c, 0, 0, 0);
}

#define SH(V,I)  __builtin_shufflevector(V, V, 2*(I), 2*(I)+1)
#define H2X(F)   __builtin_bit_cast(h2, F)
#define SL(CG)   (4*((CG) + ((CG)>>3)))

// decoder 2-row dot2 group (R10)
#define DPAIR2(LOV, HIV, R0, R1) { \
    h2 c0=SH(LOV,0), c1=SH(LOV,1), c2=SH(LOV,2), c3=SH(LOV,3); \
    h2 c4=SH(HIV,0), c5=SH(HIV,1), c6=SH(HIV,2), c7=SH(HIV,3); \
    a00.x=fdot2(R0,c0,a00.x); a00.y=fdot2(R0,c1,a00.y); a00.z=fdot2(R0,c2,a00.z); a00.w=fdot2(R0,c3,a00.w); \
    a01.x=fdot2(R0,c4,a01.x); a01.y=fdot2(R0,c5,a01.y); a01.z=fdot2(R0,c6,a01.z); a01.w=fdot2(R0,c7,a01.w); \
    a10.x=fdot2(R1,c0,a10.x); a10.y=fdot2(R1,c1,a10.y); a10.z=fdot2(R1,c2,a10.z); a10.w=fdot2(R1,c3,a10.w); \
    a11.x=fdot2(R1,c4,a11.x); a11.y=fdot2(R1,c5,a11.y); a11.z=fdot2(R1,c6,a11.z); a11.w=fdot2(R1,c7,a11.w); \
}

// ---------------- prep ----------------
struct PrepArgs {
    const float *We, *Wi, *Vd, *eWih, *eWhh, *eBih, *eBhh,
                *mWih, *mWhh, *mBih, *mBhh, *Wx, *Wh, *dWih, *dWhh, *dBih, *dBhh;
};

__global__ void prep_kernel(PrepArgs a, float* __restrict__ ws) {
    int sec  = blockIdx.x >> 2;
    int base = (blockIdx.x & 3) * blockDim.x + threadIdx.x;
    const int stride = blockDim.x * 4;
    switch (sec) {
        case 0: { // We [128][256] -> WmT[n][0:256]
            _Float16* hd = (_Float16*)(ws + OFF_WMT);
            for (int o = base; o < 128 * 256; o += stride) {
                int n = o >> 8, k = o & 255;
                hd[n * 320 + k] = (_Float16)a.We[o];
            }
        } return;
        case 1: { // Wi [128][64] -> WmT[n][256:320]
            _Float16* hd = (_Float16*)(ws + OFF_WMT);
            for (int o = base; o < 128 * 64; o += stride) {
                int n = o >> 6, k = o & 63;
                hd[n * 320 + 256 + k] = (_Float16)a.Wi[o];
            }
        } return;
        case 2: { _Float16* hd = (_Float16*)(ws + OFF_VdT);
                  for (int o = base; o < 64 * 128; o += stride) hd[o] = (_Float16)a.Vd[o]; } return;
        case 3: { _Float16* hd = (_Float16*)(ws + OFF_eWihT);
                  for (int o = base; o < 512 * 64; o += stride) hd[o] = (_Float16)a.eWih[o]; } return;
        case 4: { _Float16* hd = (_Float16*)(ws + OFF_eWhhT);
                  for (int o = base; o < 512 * 128; o += stride) hd[o] = (_Float16)a.eWhh[o]; } return;
        case 5: { _Float16* hd = (_Float16*)(ws + OFF_mWihT);
                  for (int o = base; o < 512 * 128; o += stride) hd[o] = (_Float16)a.mWih[o]; } return;
        case 6: { _Float16* hd = (_Float16*)(ws + OFF_mWhhT);
                  for (int o = base; o < 512 * 128; o += stride) hd[o] = (_Float16)a.mWhh[o]; } return;
        case 7: { _Float16* hd = (_Float16*)(ws + OFF_WxT);
                  for (int o = base; o < 128 * 128; o += stride) hd[o] = (_Float16)a.Wx[o]; } return;
        case 8: { // Wh [128][256] pair-packed for decoder
            _Float16* hd = (_Float16*)(ws + OFF_WhT);
            for (int o = base; o < 128 * 256; o += stride) {
                int r = o % 128, c = o / 128;
                hd[(c >> 1) * 256 + 2 * r + (c & 1)] = (_Float16)a.Wh[r * 256 + c];
            }
        } return;
        case 9: { _Float16* hd = (_Float16*)(ws + OFF_dWihT);
            for (int o = base; o < 512 * 128; o += stride) {
                int r = o % 512, c = o / 512;
                hd[(c >> 1) * 1024 + 2 * r + (c & 1)] = (_Float16)a.dWih[r * 128 + c];
            }
        } return;
        case 10: { _Float16* hd = (_Float16*)(ws + OFF_dWhhT);
            for (int o = base; o < 512 * 128; o += stride) {
                int r = o % 512, c = o / 512;
                hd[(c >> 1) * 1024 + 2 * r + (c & 1)] = (_Float16)a.dWhh[r * 128 + c];
            }
        } return;
        case 11: for (int i = base; i < 512; i += stride) ws[OFF_ENCB + i] = a.eBih[i] + a.eBhh[i]; return;
        case 12: for (int i = base; i < 512; i += stride) ws[OFF_MIDB + i] = a.mBih[i] + a.mBhh[i]; return;
        case 13: for (int i = base; i < 512; i += stride) ws[OFF_DECB + i] = a.dBih[i] + a.dBhh[i]; return;
        default: return;
    }
}

// ---------------- persistent encoder + mid LSTM: 256 blocks x 512 thr (8 waves), 4 rows/block ----------------
// All matmuls on MFMA 16x16x32 f16 (M=16, rows 0-3 valid). B streamed from global [N][K] fp16.
// A-buffer row pads (+8 halves) keep ds_read_b128 16B-aligned and 2-way-bank-max.
#define SA_ 328   // hcx16 row stride (h 0..127 | c 128..255 | x 256..319)
#define SB_ 136   // avbuf / hmbuf row stride
#define SX_ 72    // xinbuf row stride

__global__ __launch_bounds__(512, 1) void enc_mid_kernel(
    const float* __restrict__ x_all,
    const float* __restrict__ Wi_b,
    const float* __restrict__ Vd_b,
    const float* __restrict__ Wx_b,
    float* __restrict__ ws)
{
    __shared__ __align__(16) _Float16 hcx16[16 * SA_];
    __shared__ __align__(16) _Float16 avbuf[16 * SB_];
    __shared__ __align__(16) _Float16 xinbuf[16 * SX_];
    __shared__ __align__(16) _Float16 hmbuf[16 * SB_];
    __shared__ __align__(16) float cE[4][H_], cM[4][H_];
    __shared__ __align__(16) float xf[4][F_], xnext[4][F_];
    __shared__ __align__(16) float s_ws[4][F_];
    __shared__ __align__(16) float wxsta[4][H_];
    __shared__ float bWi[H_], bVd[F_], bWx[H_], bE[G_], bM[G_];

    const int tid  = threadIdx.x;
    const int wv   = tid >> 6;
    const int lane = tid & 63;
    const int l16  = lane & 15;
    const int q8   = (lane >> 4) * 8;
    const int b0   = blockIdx.x * 4;

    for (int i = tid; i < 16 * SA_; i += 512) hcx16[i] = (_Float16)0.f;
    for (int i = tid; i < 16 * SB_; i += 512) { avbuf[i] = (_Float16)0.f; hmbuf[i] = (_Float16)0.f; }
    for (int i = tid; i < 16 * SX_; i += 512) xinbuf[i] = (_Float16)0.f;
    ((float*)cE)[tid] = 0.f; ((float*)cM)[tid] = 0.f;
    if (tid < H_) { bWi[tid] = Wi_b[tid]; bWx[tid] = Wx_b[tid]; }
    if (tid < F_) bVd[tid] = Vd_b[tid];
    bE[tid] = ws[OFF_ENCB + tid];
    bM[tid] = ws[OFF_MIDB + tid];
    if (tid < 256) {  // x for t=0
        int r = tid >> 6, f = tid & 63;
        float v = x_all[((b0 + r) * TE + 0) * F_ + f];
        xf[r][f] = v;
        hcx16[r * SA_ + 256 + f] = (_Float16)v;
    }
    __syncthreads();

    const _Float16* WmH   = (const _Float16*)(ws + OFF_WMT);    // [128][320]
    const _Float16* VdH   = (const _Float16*)(ws + OFF_VdT);    // [64][128]
    const _Float16* eWihH = (const _Float16*)(ws + OFF_eWihT);  // [512][64]
    const _Float16* eWhhH = (const _Float16*)(ws + OFF_eWhhT);  // [512][128]
    const _Float16* mWihH = (const _Float16*)(ws + OFF_mWihT);  // [512][128]
    const _Float16* mWhhH = (const _Float16*)(ws + OFF_mWhhT);  // [512][128]
    const _Float16* WxHH  = (const _Float16*)(ws + OFF_WxT);    // [128][128]
    _Float16* midH = (_Float16*)(ws + OFF_MID);
    _Float16* wxH  = (_Float16*)(ws + OFF_WX);

    for (int t = 0; t < TE; ++t) {
        // ---- P1: av = tanh([h|c|x] @ WmT + bWi)  (N=128: tile wv; K=320: 10 ksteps)
        {
            f4v acc = {0.f, 0.f, 0.f, 0.f};
            const _Float16* ap = hcx16 + l16 * SA_ + q8;
            const _Float16* bp = WmH + (wv * 16 + l16) * 320 + q8;
            #pragma unroll
            for (int ks = 0; ks < 10; ++ks)
                acc = mfma16(*(const h8*)(ap + ks * 32), *(const h8*)(bp + ks * 32), acc);
            if (lane < 16) {
                int j = wv * 16 + lane;
                #pragma unroll
                for (int r = 0; r < 4; ++r)
                    avbuf[r * SB_ + j] = (_Float16)tanh_fast(acc[r] + bWi[j]);
            }
        }
        __syncthreads();

        // ---- P2: s = av @ VdT + bVd  (waves 0-3; N=64; K=128); waves 4-7 prefetch x_{t+1}
        if (wv < 4) {
            f4v acc = {0.f, 0.f, 0.f, 0.f};
            const _Float16* ap = avbuf + l16 * SB_ + q8;
            const _Float16* bp = VdH + (wv * 16 + l16) * 128 + q8;
            #pragma unroll
            for (int ks = 0; ks < 4; ++ks)
                acc = mfma16(*(const h8*)(ap + ks * 32), *(const h8*)(bp + ks * 32), acc);
            if (lane < 16) {
                int j = wv * 16 + lane;
                #pragma unroll
                for (int r = 0; r < 4; ++r) s_ws[r][j] = acc[r] + bVd[j];
            }
        } else if (t + 1 < TE) {
            int q = tid - 256, r = q >> 6, f = q & 63;
            xnext[r][f] = x_all[((b0 + r) * TE + (t + 1)) * F_ + f];
        }
        __syncthreads();

        // ---- P3: softmax over 64 -> xin (fp16 A-layout)
        if (tid < 256) {
            int j = tid & 63, r = tid >> 6;
            float acc = s_ws[r][j];
            float m = acc;
            for (int off = 32; off > 0; off >>= 1) m = fmaxf(m, __shfl_xor(m, off, 64));
            float e = fexp2((acc - m) * LOG2E);
            float ssum = e;
            for (int off = 32; off > 0; off >>= 1) ssum += __shfl_xor(ssum, off, 64);
            xinbuf[r * SX_ + j] = (_Float16)(xf[r][j] * e * frcp(ssum));
        }
        __syncthreads();

        // ---- P4: enc gates = xin@eWih^T + h@eWhh^T; cell in-register
        // wave wv owns N-tiles {wv, wv+8, wv+16, wv+24} -> (gi,gf,gg,go) for cols wv*16..+15
        float hn[4], cn[4];
        {
            f4v ac0 = {0.f,0.f,0.f,0.f}, ac1 = ac0, ac2 = ac0, ac3 = ac0;
            {
                const _Float16* ap = xinbuf + l16 * SX_ + q8;
                const _Float16* bp = eWihH + (wv * 16 + l16) * 64 + q8;   // tile stride 128*64 = 8192
                #pragma unroll
                for (int ks = 0; ks < 2; ++ks) {
                    h8 a = *(const h8*)(ap + ks * 32);
                    ac0 = mfma16(a, *(const h8*)(bp +         ks * 32), ac0);
                    ac1 = mfma16(a, *(const h8*)(bp +  8192 + ks * 32), ac1);
                    ac2 = mfma16(a, *(const h8*)(bp + 16384 + ks * 32), ac2);
                    ac3 = mfma16(a, *(const h8*)(bp + 24576 + ks * 32), ac3);
                }
            }
            {
                const _Float16* ap = hcx16 + l16 * SA_ + q8;
                const _Float16* bp = eWhhH + (wv * 16 + l16) * 128 + q8;  // tile stride 128*128 = 16384
                #pragma unroll
                for (int ks = 0; ks < 4; ++ks) {
                    h8 a = *(const h8*)(ap + ks * 32);
                    ac0 = mfma16(a, *(const h8*)(bp +         ks * 32), ac0);
                    ac1 = mfma16(a, *(const h8*)(bp + 16384 + ks * 32), ac1);
                    ac2 = mfma16(a, *(const h8*)(bp + 32768 + ks * 32), ac2);
                    ac3 = mfma16(a, *(const h8*)(bp + 49152 + ks * 32), ac3);
                }
            }
            if (lane < 16) {
                int j = wv * 16 + lane;
                #pragma unroll
                for (int r = 0; r < 4; ++r) {
                    float gi = ac0[r] + bE[j];
                    float gf = ac1[r] + bE[j + 128];
                    float gg = ac2[r] + bE[j + 256];
                    float go = ac3[r] + bE[j + 384];
                    float c = sigm(gf) * cE[r][j] + sigm(gi) * tanh_fast(gg);
                    hn[r] = sigm(go) * tanh_fast(c);
                    cn[r] = c;
                }
            }
        }
        __syncthreads();   // all waves done reading old h/c
        if (lane < 16) {
            int j = wv * 16 + lane;
            #pragma unroll
            for (int r = 0; r < 4; ++r) {
                cE[r][j] = cn[r];
                hcx16[r * SA_ + j]       = (_Float16)hn[r];
                hcx16[r * SA_ + 128 + j] = (_Float16)cn[r];
            }
        }
        __syncthreads();

        // ---- P5: mid gates = h_enc@mWih^T + h_mid@mWhh^T; cell in-register
        {
            f4v ac0 = {0.f,0.f,0.f,0.f}, ac1 = ac0, ac2 = ac0, ac3 = ac0;
            {
                const _Float16* ap = hcx16 + l16 * SA_ + q8;
                const _Float16* bp = mWihH + (wv * 16 + l16) * 128 + q8;
                #pragma unroll
                for (int ks = 0; ks < 4; ++ks) {
                    h8 a = *(const h8*)(ap + ks * 32);
                    ac0 = mfma16(a, *(const h8*)(bp +         ks * 32), ac0);
                    ac1 = mfma16(a, *(const h8*)(bp + 16384 + ks * 32), ac1);
                    ac2 = mfma16(a, *(const h8*)(bp + 32768 + ks * 32), ac2);
                    ac3 = mfma16(a, *(const h8*)(bp + 49152 + ks * 32), ac3);
                }
            }
            {
                const _Float16* ap = hmbuf + l16 * SB_ + q8;
                const _Float16* bp = mWhhH + (wv * 16 + l16) * 128 + q8;
                #pragma unroll
                for (int ks = 0; ks < 4; ++ks) {
                    h8 a = *(const h8*)(ap + ks * 32);
                    ac0 = mfma16(a, *(const h8*)(bp +         ks * 32), ac0);
                    ac1 = mfma16(a, *(const h8*)(bp + 16384 + ks * 32), ac1);
                    ac2 = mfma16(a, *(const h8*)(bp + 32768 + ks * 32), ac2);
                    ac3 = mfma16(a, *(const h8*)(bp + 49152 + ks * 32), ac3);
                }
            }
            if (lane < 16) {
                int j = wv * 16 + lane;
                #pragma unroll
                for (int r = 0; r < 4; ++r) {
                    float gi = ac0[r] + bM[j];
                    float gf = ac1[r] + bM[j + 128];
                    float gg = ac2[r] + bM[j + 256];
                    float go = ac3[r] + bM[j + 384];
                    float c = sigm(gf) * cM[r][j] + sigm(gi) * tanh_fast(gg);
                    hn[r] = sigm(go) * tanh_fast(c);
                    cn[r] = c;
                }
            }
        }
        __syncthreads();   // all waves done reading old h_mid
        if (lane < 16) {
            int j = wv * 16 + lane;
            #pragma unroll
            for (int r = 0; r < 4; ++r) {
                cM[r][j] = cn[r];
                hmbuf[r * SB_ + j] = (_Float16)hn[r];
            }
        }
        __syncthreads();

        // ---- P6: wx = h_mid @ WxT + bWx  (N=128: tile wv; K=128)
        {
            f4v acc = {0.f, 0.f, 0.f, 0.f};
            const _Float16* ap = hmbuf + l16 * SB_ + q8;
            const _Float16* bp = WxHH + (wv * 16 + l16) * 128 + q8;
            #pragma unroll
            for (int ks = 0; ks < 4; ++ks)
                acc = mfma16(*(const h8*)(ap + ks * 32), *(const h8*)(bp + ks * 32), acc);
            if (lane < 16) {
                int j = wv * 16 + lane;
                #pragma unroll
                for (int r = 0; r < 4; ++r) wxsta[r][j] = acc[r] + bWx[j];
            }
        }
        __syncthreads();

        // ---- P7: coalesced global stores of mid & wx + install prefetched x
        {
            int r = tid >> 7, j = tid & 127;
            size_t o = ((size_t)(b0 + r) * TE + t) * H_ + j;
            midH[o] = hmbuf[r * SB_ + j];
            wxH[o]  = (_Float16)wxsta[r][j];
            if (tid < 256 && t + 1 < TE) {
                int rr = tid >> 6, f = tid & 63;
                float v = xnext[rr][f];
                xf[rr][f] = v;
                hcx16[rr * SA_ + 256 + f] = (_Float16)v;
            }
        }
        __syncthreads();
    }

    {
        int j = tid & 127, r = tid >> 7;
        ws[OFF_STH + (b0 + r) * H_ + j] = (float)hmbuf[r * SB_ + j];
        ws[OFF_STC + (b0 + r) * H_ + j] = cM[r][j];
    }
}

// ---------------- persistent decoder: 512 blocks x 512 thr, 2 rows/block (R10, unchanged) ----------------
#define QP_ 132

__global__ __launch_bounds__(512, 2) void dec_kernel(
    const float* __restrict__ Vw_in,
    const float* __restrict__ Vb_in,
    const float* __restrict__ rw_in,
    const float* __restrict__ rb_in,
    const float* __restrict__ ws,
    float* __restrict__ out)
{
    __shared__ __align__(16) float scr[9216];
    __shared__ __align__(16) float hc2[2][H2_];
    __shared__ __align__(16) float qv[2][QP_];
    __shared__ __align__(16) float sb[2][TE];
    __shared__ __align__(16) float dinp[8][2][H_];
    __shared__ float bD[G_], Vw[H_], rw[H_];

    const int tid = threadIdx.x;
    const int b0  = blockIdx.x * 2;
    const float Vb = Vb_in[0], rb = rb_in[0];

    {
        int r = tid >> 8, c = tid & 255;
        hc2[r][c] = (c < H_) ? ws[OFF_STH + (b0 + r) * H_ + c]
                             : ws[OFF_STC + (b0 + r) * H_ + (c - H_)];
    }
    if (tid < H_) { Vw[tid] = Vw_in[tid]; rw[tid] = rw_in[tid]; }
    bD[tid] = ws[OFF_DECB + tid];
    __syncthreads();

    const h8* WhH2  = (const h8*)(ws + OFF_WhT);
    const h8* dWih2 = (const h8*)(ws + OFF_dWihT);
    const h8* dWhh2 = (const h8*)(ws + OFF_dWhhT);
    const h8* wx8   = (const h8*)(ws + OFF_WX);
    const h4* mid4  = (const h4*)(ws + OFF_MID);

    for (int td = 0; td < TD; ++td) {
        // P1: q partials
        {
            int cg = tid & 15, ks = tid >> 4;
            int p0 = ks * 4;
            float4 a00 = make_float4(0.f,0.f,0.f,0.f), a01 = a00, a10 = a00, a11 = a00;
            #pragma unroll
            for (int i = 0; i < 4; ++i) {
                int p = p0 + i;
                h8 lo = WhH2[p * 32 + cg * 2];
                h8 hi = WhH2[p * 32 + cg * 2 + 1];
                h2 r0; r0[0] = (_Float16)hc2[0][2*p]; r0[1] = (_Float16)hc2[0][2*p+1];
                h2 r1; r1[0] = (_Float16)hc2[1][2*p]; r1[1] = (_Float16)hc2[1][2*p+1];
                DPAIR2(lo, hi, r0, r1);
            }
            int sl = SL(cg);
            float* sp = scr + ks * 288;
            *(float4*)(sp +       sl) = a00; *(float4*)(sp +  72 + sl) = a01;
            *(float4*)(sp + 144 + sl) = a10; *(float4*)(sp + 216 + sl) = a11;
        }
        __syncthreads();
        if (tid < 256) {
            int j = tid & 127, r = tid >> 7;
            int e = j & 7, cgj = j >> 3;
            int idx = r * 144 + ((e < 4) ? SL(cgj) + e : 72 + SL(cgj) + (e - 4));
            float v = 0.f;
            #pragma unroll
            for (int ks = 0; ks < 32; ++ks) v += scr[ks * 288 + idx];
            qv[r][j] = v;
        }
        __syncthreads();

        // P2: scores
        for (int task = tid; task < 2 * TE; task += 512) {
            int r = (task >= TE) ? 1 : 0;
            int tp = task - r * TE;
            const h8* wxr = wx8 + ((size_t)(b0 + r) * TE + tp) * 16;
            float acc = Vb;
            #pragma unroll 4
            for (int kk = 0; kk < 16; ++kk) {
                h8 hv = wxr[kk];
                int j = kk * 8;
                float4 q0 = *(const float4*)&qv[r][j], q1 = *(const float4*)&qv[r][j + 4];
                float4 v0 = *(const float4*)&Vw[j],    v1 = *(const float4*)&Vw[j + 4];
                acc += tanh_fast(q0.x + (float)hv[0]) * v0.x + tanh_fast(q0.y + (float)hv[1]) * v0.y
                     + tanh_fast(q0.z + (float)hv[2]) * v0.z + tanh_fast(q0.w + (float)hv[3]) * v0.w;
                acc += tanh_fast(q1.x + (float)hv[4]) * v1.x + tanh_fast(q1.y + (float)hv[5]) * v1.y
                     + tanh_fast(q1.z + (float)hv[6]) * v1.z + tanh_fast(q1.w + (float)hv[7]) * v1.w;
            }
            sb[r][tp] = acc;
        }
        __syncthreads();

        // P3: dec_in partials
        {
            int ts = tid >> 6, r = (tid >> 5) & 1, cg = tid & 31;
            int t0 = ts * 21;
            float4 a = make_float4(0.f, 0.f, 0.f, 0.f);
            #pragma unroll 3
            for (int tp = t0; tp < t0 + 21; ++tp) {
                float s = sb[r][tp];
                h4 m = mid4[((size_t)(b0 + r) * TE + tp) * 32 + cg];
                float4 mf;
                mf.x = (float)m[0]; mf.y = (float)m[1]; mf.z = (float)m[2]; mf.w = (float)m[3];
                fma4(a, mf, s);
            }
            *(float4*)&dinp[ts][r][cg * 4] = a;
        }
        __syncthreads();
        if (tid < 256) {
            int j = tid & 127, r = tid >> 7;
            qv[r][j] = ((dinp[0][r][j] + dinp[1][r][j]) + (dinp[2][r][j] + dinp[3][r][j]))
                     + ((dinp[4][r][j] + dinp[5][r][j]) + (dinp[6][r][j] + dinp[7][r][j]));
        }
        __syncthreads();

        // P4: gate partials
        {
            int cg = tid & 63, ks = tid >> 6;
            int p0 = ks * 8;
            float4 a00 = make_float4(0.f,0.f,0.f,0.f), a01 = a00, a10 = a00, a11 = a00;
            #pragma unroll 4
            for (int i = 0; i < 8; ++i) {
                int p = p0 + i;
                h8 lo = dWih2[p * 128 + cg * 2];
                h8 hi = dWih2[p * 128 + cg * 2 + 1];
                h2 r0; r0[0] = (_Float16)qv[0][2*p]; r0[1] = (_Float16)qv[0][2*p+1];
                h2 r1; r1[0] = (_Float16)qv[1][2*p]; r1[1] = (_Float16)qv[1][2*p+1];
                DPAIR2(lo, hi, r0, r1);
            }
            #pragma unroll 4
            for (int i = 0; i < 8; ++i) {
                int p = p0 + i;
                h8 lo = dWhh2[p * 128 + cg * 2];
                h8 hi = dWhh2[p * 128 + cg * 2 + 1];
                h2 r0; r0[0] = (_Float16)hc2[0][2*p]; r0[1] = (_Float16)hc2[0][2*p+1];
                h2 r1; r1[0] = (_Float16)hc2[1][2*p]; r1[1] = (_Float16)hc2[1][2*p+1];
                DPAIR2(lo, hi, r0, r1);
            }
            int sl = SL(cg);
            float* sp = scr + ks * 1152;
            *(float4*)(sp +       sl) = a00; *(float4*)(sp + 288 + sl) = a01;
            *(float4*)(sp + 576 + sl) = a10; *(float4*)(sp + 864 + sl) = a11;
        }
        __syncthreads();

        // P5: combine + LSTM update
        if (tid < 256) {
            int j = tid & 127, r = tid >> 7;
            int e = j & 7, cgj = j >> 3;
            int i0, i1, i2, i3;
            {
                int c0 = cgj, c1 = 16 + cgj, c2 = 32 + cgj, c3 = 48 + cgj;
                i0 = (e < 4) ? SL(c0) + e : 288 + SL(c0) + (e - 4);
                i1 = (e < 4) ? SL(c1) + e : 288 + SL(c1) + (e - 4);
                i2 = (e < 4) ? SL(c2) + e : 288 + SL(c2) + (e - 4);
                i3 = (e < 4) ? SL(c3) + e : 288 + SL(c3) + (e - 4);
            }
            const float* sp = scr + r * 576;
            float gi = bD[j], gf = bD[j + 128], gg = bD[j + 256], go = bD[j + 384];
            #pragma unroll
            for (int ks = 0; ks < 8; ++ks) {
                const float* p = sp + ks * 1152;
                gi += p[i0]; gf += p[i1]; gg += p[i2]; go += p[i3];
            }
            float c = sigm(gf) * hc2[r][H_ + j] + sigm(gi) * tanh_fast(gg);
            float h = sigm(go) * tanh_fast(c);
            hc2[r][H_ + j] = c; hc2[r][j] = h;
        }
        __syncthreads();

        // P6: output dot
        if (tid < 128) {
            int r = tid >> 6, lane = tid & 63;
            float v = hc2[r][lane] * rw[lane] + hc2[r][lane + 64] * rw[lane + 64];
            for (int off = 32; off > 0; off >>= 1) v += __shfl_xor(v, off, 64);
            if (lane == 0) out[(b0 + r) * TD + td] = v + rb;
        }
    }
}

extern "C" void kernel_launch(void* const* d_in, const int* in_sizes, int n_in,
                              void* d_out, int out_size, void* d_ws, size_t ws_size,
                              hipStream_t stream)
{
    (void)in_sizes; (void)n_in; (void)out_size;
    if (ws_size < (size_t)WS_FLOATS * sizeof(float)) return;

    const float* x_all = (const float*)d_in[0];
    const float* Wi_b  = (const float*)d_in[3];
    const float* Vd_b  = (const float*)d_in[6];
    const float* Wx_b  = (const float*)d_in[16];
    const float* V_w   = (const float*)d_in[18];
    const float* V_b   = (const float*)d_in[19];
    const float* reg_w = (const float*)d_in[24];
    const float* reg_b = (const float*)d_in[25];
    float* ws  = (float*)d_ws;
    float* out = (float*)d_out;

    PrepArgs pa{
        (const float*)d_in[4],  // We_w
        (const float*)d_in[2],  // Wi_w
        (const float*)d_in[5],  // Vd_w
        (const float*)d_in[7],  // enc_Wih
        (const float*)d_in[8],  // enc_Whh
        (const float*)d_in[9],  // enc_bih
        (const float*)d_in[10], // enc_bhh
        (const float*)d_in[11], // mid_Wih
        (const float*)d_in[12], // mid_Whh
        (const float*)d_in[13], // mid_bih
        (const float*)d_in[14], // mid_bhh
        (const float*)d_in[15], // Wx_w
        (const float*)d_in[17], // Wh_w
        (const float*)d_in[20], // dec_Wih
        (const float*)d_in[21], // dec_Whh
        (const float*)d_in[22], // dec_bih
        (const float*)d_in[23]  // dec_bhh
    };

    prep_kernel<<<56, 256, 0, stream>>>(pa, ws);
    enc_mid_kernel<<<256, 512, 0, stream>>>(x_all, Wi_b, Vd_b, Wx_b, ws);
    dec_kernel<<<512, 512, 0, stream>>>(V_w, V_b, reg_w, reg_b, ws, out);
}